// Round 4
// baseline (299.172 us; speedup 1.0000x reference)
//
#include <hip/hip_runtime.h>

#define N_NODES 10000
#define N_EDGES 640000
#define D 128

#define GEMM_BLOCKS 157   // 64 nodes per block
#define PREP_BLOCKS 64
#define SPMM_BLOCKS 250
#define RPB 40            // rows per spmm block (250 * 40 = 10000)
#define QCAP 192          // per-row LDS queue cap (mean 64, +16 sigma)

typedef unsigned int uint32;
typedef unsigned short u16;

__device__ __forceinline__ uint32 f2bf_bits(float f) {
    uint32 u = __float_as_uint(f);
    return (u + 0x7FFFu + ((u >> 16) & 1u)) >> 16;   // RNE bf16 bits
}
__device__ __forceinline__ uint32 pack2(float lo, float hi) {
    return f2bf_bits(lo) | (f2bf_bits(hi) << 16);
}
__device__ __forceinline__ void fma4(float4& a, float s, const float4& b) {
    a.x += s * b.x; a.y += s * b.y; a.z += s * b.z; a.w += s * b.w;
}

// Fused launch: blocks [0,GEMM_BLOCKS) compute h2 = pack_bf16(x @ W);
// blocks [GEMM_BLOCKS, +PREP_BLOCKS) pack row->u16 and (col,val)->rec
// (col u16 | bf16(val)<<16). No histogram/scan needed anymore.
__global__ __launch_bounds__(256) void gemm_prep_kernel(
    const float* __restrict__ x, const float* __restrict__ w,
    const int* __restrict__ row, const int* __restrict__ col,
    const float* __restrict__ val,
    uint32* __restrict__ h2, u16* __restrict__ row16, uint32* __restrict__ rec)
{
    if (blockIdx.x >= GEMM_BLOCKS) {
        const int tid = (blockIdx.x - GEMM_BLOCKS) * 256 + threadIdx.x;
        const int stride = PREP_BLOCKS * 256;
        const int4*   row4 = (const int4*)row;
        const int4*   col4 = (const int4*)col;
        const float4* val4 = (const float4*)val;
        uint2* r16q = (uint2*)row16;
        uint4* rec4 = (uint4*)rec;
        for (int i = tid; i < N_EDGES / 4; i += stride) {
            int4 r = row4[i]; int4 c = col4[i]; float4 v = val4[i];
            rec4[i] = make_uint4(
                (uint32)c.x | (f2bf_bits(v.x) << 16),
                (uint32)c.y | (f2bf_bits(v.y) << 16),
                (uint32)c.z | (f2bf_bits(v.z) << 16),
                (uint32)c.w | (f2bf_bits(v.w) << 16));
            r16q[i] = make_uint2((uint32)r.x | ((uint32)r.y << 16),
                                 (uint32)r.z | ((uint32)r.w << 16));
        }
        return;
    }

    // ---- GEMM: 64 nodes/block, thread (nl=t>>3, cg=t&7) does 2 nodes x 16
    // cols {4cg+32m+q}. W float4 reads start at bank 4*cg; 8 col-groups span
    // all 32 banks, same-cg lanes broadcast => conflict-free. (passed R2/R3)
    __shared__ float Wf[D * D];  // 64 KB
    const int t = threadIdx.x;
    #pragma unroll
    for (int j = 0; j < 16; ++j) {
        int idx = t + j * 256;
        *(float4*)&Wf[idx * 4] = *(const float4*)&w[idx * 4];
    }
    __syncthreads();

    const int nl = t >> 3;
    const int cg = t & 7;
    const int n0 = blockIdx.x * 64 + nl * 2;
    const int n1 = n0 + 1;
    const int c0 = (n0 < N_NODES) ? n0 : (N_NODES - 1);
    const int c1 = (n1 < N_NODES) ? n1 : (N_NODES - 1);
    const float* xr0 = x + (long)c0 * D;
    const float* xr1 = x + (long)c1 * D;

    float4 a0 = {0,0,0,0}, a1 = {0,0,0,0}, a2 = {0,0,0,0}, a3 = {0,0,0,0};
    float4 b0 = {0,0,0,0}, b1 = {0,0,0,0}, b2 = {0,0,0,0}, b3 = {0,0,0,0};
    #pragma unroll 4
    for (int k4 = 0; k4 < D / 4; ++k4) {
        float4 xa = *(const float4*)&xr0[k4 * 4];
        float4 xb = *(const float4*)&xr1[k4 * 4];
        #pragma unroll
        for (int j = 0; j < 4; ++j) {
            float av = (j == 0) ? xa.x : (j == 1) ? xa.y : (j == 2) ? xa.z : xa.w;
            float bv = (j == 0) ? xb.x : (j == 1) ? xb.y : (j == 2) ? xb.z : xb.w;
            const float* wr = &Wf[(k4 * 4 + j) * D + cg * 4];
            float4 w0 = *(const float4*)(wr);
            float4 w1 = *(const float4*)(wr + 32);
            float4 w2 = *(const float4*)(wr + 64);
            float4 w3 = *(const float4*)(wr + 96);
            fma4(a0, av, w0); fma4(a1, av, w1); fma4(a2, av, w2); fma4(a3, av, w3);
            fma4(b0, bv, w0); fma4(b1, bv, w1); fma4(b2, bv, w2); fma4(b3, bv, w3);
        }
    }
    if (n0 < N_NODES) {
        uint32* base = h2 + (long)n0 * 64;
        *(uint2*)(base + 2*cg)      = make_uint2(pack2(a0.x,a0.y), pack2(a0.z,a0.w));
        *(uint2*)(base + 2*cg + 16) = make_uint2(pack2(a1.x,a1.y), pack2(a1.z,a1.w));
        *(uint2*)(base + 2*cg + 32) = make_uint2(pack2(a2.x,a2.y), pack2(a2.z,a2.w));
        *(uint2*)(base + 2*cg + 48) = make_uint2(pack2(a3.x,a3.y), pack2(a3.z,a3.w));
    }
    if (n1 < N_NODES) {
        uint32* base = h2 + (long)n1 * 64;
        *(uint2*)(base + 2*cg)      = make_uint2(pack2(b0.x,b0.y), pack2(b0.z,b0.w));
        *(uint2*)(base + 2*cg + 16) = make_uint2(pack2(b1.x,b1.y), pack2(b1.z,b1.w));
        *(uint2*)(base + 2*cg + 32) = make_uint2(pack2(b2.x,b2.y), pack2(b2.z,b2.w));
        *(uint2*)(base + 2*cg + 48) = make_uint2(pack2(b3.x,b3.y), pack2(b3.z,b3.w));
    }
}

// Owner-computes SpMM: block owns rows [lo, lo+40). Phase A: scan the packed
// u16 row stream (depth-2 pipelined uint4 loads = 8 edges each), append
// matching edges' rec words to per-row LDS queues. Phase B: wave w handles
// rows w, w+4, ...: per edge one wave-uniform LDS read + one coalesced 256B
// h2 gather, accumulate in registers, write out[row] directly (+bias).
// Zero global atomics, zero scattered global writes.
__global__ __launch_bounds__(256) void spmm_kernel(
    const u16* __restrict__ row16, const uint32* __restrict__ rec,
    const uint32* __restrict__ h2, const float* __restrict__ bias,
    float* __restrict__ out)
{
    __shared__ uint32 qrec[RPB * QCAP];   // 30720 B
    __shared__ int qcnt[RPB];
    const int t  = threadIdx.x;
    const int lo = blockIdx.x * RPB;
    if (t < RPB) qcnt[t] = 0;
    __syncthreads();

    // Phase A
    const uint4* r16q = (const uint4*)row16;   // 8 edges / load
    const int NQ = N_EDGES / 8;                // 80000
    int i = t;
    if (i < NQ) {
        uint4 p = r16q[i];
        while (true) {
            int inext = i + 256;
            uint4 pn;
            if (inext < NQ) pn = r16q[inext];   // prefetch (2 in flight/lane)
            const int e = i * 8;
            uint32 wds[4] = {p.x, p.y, p.z, p.w};
            #pragma unroll
            for (int j = 0; j < 4; ++j) {
                int r0 = (int)(wds[j] & 0xFFFFu) - lo;
                int r1 = (int)(wds[j] >> 16) - lo;
                if ((unsigned)r0 < (unsigned)RPB) {
                    int pos = atomicAdd(&qcnt[r0], 1);
                    if (pos < QCAP) qrec[r0 * QCAP + pos] = rec[e + 2*j];
                }
                if ((unsigned)r1 < (unsigned)RPB) {
                    int pos = atomicAdd(&qcnt[r1], 1);
                    if (pos < QCAP) qrec[r1 * QCAP + pos] = rec[e + 2*j + 1];
                }
            }
            if (inext >= NQ) break;
            i = inext; p = pn;
        }
    }
    __syncthreads();

    // Phase B
    const int wid  = t >> 6;
    const int lane = t & 63;
    const float bb0 = bias[2 * lane];
    const float bb1 = bias[2 * lane + 1];
    for (int rl = wid; rl < RPB; rl += 4) {
        int n = qcnt[rl]; if (n > QCAP) n = QCAP;
        float a0 = 0.f, a1 = 0.f;
        #pragma unroll 8
        for (int j = 0; j < n; ++j) {
            uint32 q  = qrec[rl * QCAP + j];                 // wave-uniform
            float  v  = __uint_as_float(q & 0xFFFF0000u);    // bf16 val
            uint32 hv = h2[(q & 0xFFFFu) * 64 + lane];       // coalesced 256B
            a0 += v * __uint_as_float(hv << 16);
            a1 += v * __uint_as_float(hv & 0xFFFF0000u);
        }
        float2 o; o.x = a0 + bb0; o.y = a1 + bb1;
        *(float2*)&out[(long)(lo + rl) * D + 2 * lane] = o;
    }
}

extern "C" void kernel_launch(void* const* d_in, const int* in_sizes, int n_in,
                              void* d_out, int out_size, void* d_ws, size_t ws_size,
                              hipStream_t stream)
{
    const float* x    = (const float*)d_in[0];
    const float* aval = (const float*)d_in[1];
    const float* w    = (const float*)d_in[2];
    const float* bias = (const float*)d_in[3];
    const int* arow   = (const int*)d_in[4];
    const int* acol   = (const int*)d_in[5];

    char* ws = (char*)d_ws;
    u16*    row16 = (u16*)(ws);                 // 1,280,000 B
    uint32* rec   = (uint32*)(ws + 1280000);    // 2,560,000 B
    uint32* h2    = (uint32*)(ws + 3840000);    // 2,560,000 B  (6.4 MB total)

    gemm_prep_kernel<<<GEMM_BLOCKS + PREP_BLOCKS, 256, 0, stream>>>(
        x, w, arow, acol, aval, h2, row16, rec);
    spmm_kernel<<<SPMM_BLOCKS, 256, 0, stream>>>(
        row16, rec, h2, bias, (float*)d_out);
}

// Round 5
// 131.996 us; speedup vs baseline: 2.2665x; 2.2665x over previous
//
#include <hip/hip_runtime.h>

#define N_NODES 10000
#define N_EDGES 640000
#define D 128

#define GEMM_BLOCKS 157   // 64 nodes per block
#define SCAT_BLOCKS 99    // total 256 blocks in fused kernel
#define CAP 48            // per-(row,xcd-group) segment capacity (mean ~8)
#define OVF_CAP 8192

typedef unsigned int uint32;
typedef unsigned short u16;

__device__ __forceinline__ uint32 f2bf_bits(float f) {
    uint32 u = __float_as_uint(f);
    return (u + 0x7FFFu + ((u >> 16) & 1u)) >> 16;   // RNE bf16 bits
}
__device__ __forceinline__ uint32 pack2(float lo, float hi) {
    return f2bf_bits(lo) | (f2bf_bits(hi) << 16);
}
__device__ __forceinline__ void fma4(float4& a, float s, const float4& b) {
    a.x += s * b.x; a.y += s * b.y; a.z += s * b.z; a.w += s * b.w;
}

__device__ __forceinline__ void scat_one(int r, uint32 rc, int* my_cur,
                                         uint32* my_reg, int* ovf_cnt,
                                         uint2* ovf)
{
    int pos = atomicAdd(&my_cur[r], 1);
    if (pos < CAP) {
        my_reg[(size_t)r * CAP + pos] = rc;   // XCD-local: merges in local L2
    } else {                                   // ~never (P<1e-18), but correct
        int o = atomicAdd(ovf_cnt, 1);
        if (o < OVF_CAP) ovf[o] = make_uint2((uint32)r, rc);
    }
}

// Fused: blocks [0,157) compute h2 = pack_bf16(x @ W) (R2/R3/R4-verified GEMM);
// blocks [157,256) scatter edges into 8 XCD-group-private capacity regions.
// Group = blockIdx&7 (round-robin block->XCD => region writes stay in the
// local L2 -> full write merging; correctness holds for any mapping).
__global__ __launch_bounds__(256) void gemm_scatter_kernel(
    const float* __restrict__ x, const float* __restrict__ w,
    const int* __restrict__ row, const int* __restrict__ col,
    const float* __restrict__ val,
    uint32* __restrict__ h2, int* __restrict__ cursor,
    int* __restrict__ ovf_cnt, uint2* __restrict__ ovf,
    uint32* __restrict__ region)
{
    if (blockIdx.x >= GEMM_BLOCKS) {
        const int xcc = blockIdx.x & 7;
        int*    my_cur = cursor + xcc * N_NODES;
        uint32* my_reg = region + (size_t)xcc * N_NODES * CAP;
        const int tid    = (blockIdx.x - GEMM_BLOCKS) * 256 + threadIdx.x;
        const int stride = SCAT_BLOCKS * 256;
        const int4*   row4 = (const int4*)row;
        const int4*   col4 = (const int4*)col;
        const float4* val4 = (const float4*)val;
        for (int i = tid; i < N_EDGES / 4; i += stride) {
            int4 r = row4[i]; int4 c = col4[i]; float4 v = val4[i];
            scat_one(r.x, (uint32)c.x | (f2bf_bits(v.x) << 16), my_cur, my_reg, ovf_cnt, ovf);
            scat_one(r.y, (uint32)c.y | (f2bf_bits(v.y) << 16), my_cur, my_reg, ovf_cnt, ovf);
            scat_one(r.z, (uint32)c.z | (f2bf_bits(v.z) << 16), my_cur, my_reg, ovf_cnt, ovf);
            scat_one(r.w, (uint32)c.w | (f2bf_bits(v.w) << 16), my_cur, my_reg, ovf_cnt, ovf);
        }
        return;
    }

    // ---- GEMM: 64 nodes/block, thread (nl=t>>3, cg=t&7) does 2 nodes x 16
    // cols {4cg+32m+q}. W float4 reads start at bank 4*cg; 8 col-groups span
    // all 32 banks, same-cg lanes broadcast => conflict-free.
    __shared__ float Wf[D * D];  // 64 KB
    const int t = threadIdx.x;
    #pragma unroll
    for (int j = 0; j < 16; ++j) {
        int idx = t + j * 256;
        *(float4*)&Wf[idx * 4] = *(const float4*)&w[idx * 4];
    }
    __syncthreads();

    const int nl = t >> 3;
    const int cg = t & 7;
    const int n0 = blockIdx.x * 64 + nl * 2;
    const int n1 = n0 + 1;
    const int c0 = (n0 < N_NODES) ? n0 : (N_NODES - 1);
    const int c1 = (n1 < N_NODES) ? n1 : (N_NODES - 1);
    const float* xr0 = x + (long)c0 * D;
    const float* xr1 = x + (long)c1 * D;

    float4 a0 = {0,0,0,0}, a1 = {0,0,0,0}, a2 = {0,0,0,0}, a3 = {0,0,0,0};
    float4 b0 = {0,0,0,0}, b1 = {0,0,0,0}, b2 = {0,0,0,0}, b3 = {0,0,0,0};
    #pragma unroll 4
    for (int k4 = 0; k4 < D / 4; ++k4) {
        float4 xa = *(const float4*)&xr0[k4 * 4];
        float4 xb = *(const float4*)&xr1[k4 * 4];
        #pragma unroll
        for (int j = 0; j < 4; ++j) {
            float av = (j == 0) ? xa.x : (j == 1) ? xa.y : (j == 2) ? xa.z : xa.w;
            float bv = (j == 0) ? xb.x : (j == 1) ? xb.y : (j == 2) ? xb.z : xb.w;
            const float* wr = &Wf[(k4 * 4 + j) * D + cg * 4];
            float4 w0 = *(const float4*)(wr);
            float4 w1 = *(const float4*)(wr + 32);
            float4 w2 = *(const float4*)(wr + 64);
            float4 w3 = *(const float4*)(wr + 96);
            fma4(a0, av, w0); fma4(a1, av, w1); fma4(a2, av, w2); fma4(a3, av, w3);
            fma4(b0, bv, w0); fma4(b1, bv, w1); fma4(b2, bv, w2); fma4(b3, bv, w3);
        }
    }
    if (n0 < N_NODES) {
        uint32* base = h2 + (long)n0 * 64;
        *(uint2*)(base + 2*cg)      = make_uint2(pack2(a0.x,a0.y), pack2(a0.z,a0.w));
        *(uint2*)(base + 2*cg + 16) = make_uint2(pack2(a1.x,a1.y), pack2(a1.z,a1.w));
        *(uint2*)(base + 2*cg + 32) = make_uint2(pack2(a2.x,a2.y), pack2(a2.z,a2.w));
        *(uint2*)(base + 2*cg + 48) = make_uint2(pack2(a3.x,a3.y), pack2(a3.z,a3.w));
    }
    if (n1 < N_NODES) {
        uint32* base = h2 + (long)n1 * 64;
        *(uint2*)(base + 2*cg)      = make_uint2(pack2(b0.x,b0.y), pack2(b0.z,b0.w));
        *(uint2*)(base + 2*cg + 16) = make_uint2(pack2(b1.x,b1.y), pack2(b1.z,b1.w));
        *(uint2*)(base + 2*cg + 32) = make_uint2(pack2(b2.x,b2.y), pack2(b2.z,b2.w));
        *(uint2*)(base + 2*cg + 48) = make_uint2(pack2(b3.x,b3.y), pack2(b3.z,b3.w));
    }
}

// Wave-per-row SpMM, zero LDS, low VGPR (high occupancy — fixes R4).
// Per row: 16 independent preloads (8 counts + 8 segment loads where lane j
// holds rec j), then per edge: v_readlane broadcast (col/val scalarize to
// SGPRs) + one coalesced 256B h2 gather (L2-resident) + 2 FMA.
__global__ __launch_bounds__(256) void spmm_kernel(
    const uint32* __restrict__ region, const int* __restrict__ cursor,
    const int* __restrict__ ovf_cnt, const uint2* __restrict__ ovf,
    const uint32* __restrict__ h2, const float* __restrict__ bias,
    float* __restrict__ out)
{
    const int t = threadIdx.x;
    const int lane = t & 63;
    const int r = blockIdx.x * 4 + (t >> 6);

    int ns[8];
    uint32 recs[8];
    #pragma unroll
    for (int s = 0; s < 8; ++s) {
        int cnt = cursor[s * N_NODES + r];
        ns[s] = (cnt < CAP) ? cnt : CAP;
        // lanes 48..63 read into the next cell (harmless; region padded)
        recs[s] = region[(size_t)(s * N_NODES + r) * CAP + lane];
    }

    float a0 = 0.f, a1 = 0.f;
    #pragma unroll
    for (int s = 0; s < 8; ++s) {
        const int n = ns[s];
        for (int j = 0; j < n; ++j) {
            uint32 q = (uint32)__builtin_amdgcn_readlane((int)recs[s], j);
            float  v = __uint_as_float(q & 0xFFFF0000u);
            uint32 hv = h2[((q & 0xFFFFu) << 6) + lane];
            a0 = fmaf(v, __uint_as_float(hv << 16), a0);
            a1 = fmaf(v, __uint_as_float(hv & 0xFFFF0000u), a1);
        }
    }

    // Overflow list (expected empty; one uniform load in the common case)
    int novf = ovf_cnt[0];
    if (novf > OVF_CAP) novf = OVF_CAP;
    for (int k = 0; k < novf; ++k) {
        uint2 e = ovf[k];
        if (e.x == (uint32)r) {
            uint32 q = e.y;
            float  v = __uint_as_float(q & 0xFFFF0000u);
            uint32 hv = h2[((q & 0xFFFFu) << 6) + lane];
            a0 = fmaf(v, __uint_as_float(hv << 16), a0);
            a1 = fmaf(v, __uint_as_float(hv & 0xFFFF0000u), a1);
        }
    }

    float2 o;
    o.x = a0 + bias[2 * lane];
    o.y = a1 + bias[2 * lane + 1];
    *(float2*)&out[(size_t)r * D + 2 * lane] = o;
}

extern "C" void kernel_launch(void* const* d_in, const int* in_sizes, int n_in,
                              void* d_out, int out_size, void* d_ws, size_t ws_size,
                              hipStream_t stream)
{
    const float* x    = (const float*)d_in[0];
    const float* aval = (const float*)d_in[1];
    const float* w    = (const float*)d_in[2];
    const float* bias = (const float*)d_in[3];
    const int* arow   = (const int*)d_in[4];
    const int* acol   = (const int*)d_in[5];

    char* ws = (char*)d_ws;
    uint32* h2     = (uint32*)(ws);               // 2,560,000 B
    int*    cursor = (int*)(ws + 2560000);        //   320,000 B (8 x 10000)
    int*    ovfcnt = (int*)(ws + 2880000);        //         4 B (+pad)
    uint2*  ovf    = (uint2*)(ws + 2880064);      //    65,536 B
    uint32* region = (uint32*)(ws + 2945600);     // 15,360,000 B + 256 pad
                                                  // total ~18.3 MB

    hipMemsetAsync(ws + 2560000, 0, 320004, stream);  // cursor + ovf_cnt

    gemm_scatter_kernel<<<GEMM_BLOCKS + SCAT_BLOCKS, 256, 0, stream>>>(
        x, w, arow, acol, aval, h2, cursor, ovfcnt, ovf, region);
    spmm_kernel<<<N_NODES / 4, 256, 0, stream>>>(
        region, cursor, ovfcnt, ovf, h2, bias, (float*)d_out);
}

// Round 6
// 127.541 us; speedup vs baseline: 2.3457x; 1.0349x over previous
//
#include <hip/hip_runtime.h>

#define N_NODES 10000
#define N_EDGES 640000
#define D 128

#define GEMM_BLOCKS 157   // 64 nodes per block (MFMA)
#define SCAT_BLOCKS 99    // total 256 blocks in fused kernel
#define CAP 32            // per-(row,xcd-group) capacity (mean ~8)
#define OVF_CAP 8192
#define LSTR 136          // LDS row stride in ushorts: 272B, 16B-aligned, 2-way banks

typedef unsigned int uint32;
typedef unsigned short u16;
using short8 = __attribute__((ext_vector_type(8))) short;
using f32x4  = __attribute__((ext_vector_type(4))) float;

__device__ __forceinline__ uint32 f2bf_bits(float f) {
    uint32 u = __float_as_uint(f);
    return (u + 0x7FFFu + ((u >> 16) & 1u)) >> 16;   // RNE bf16 bits
}
__device__ __forceinline__ uint32 pack2(float lo, float hi) {
    return f2bf_bits(lo) | (f2bf_bits(hi) << 16);
}

__device__ __forceinline__ void scat_one(int r, uint32 rc, int s,
                                         int* __restrict__ cursor,
                                         uint32* __restrict__ region,
                                         int* ovf_cnt, uint2* ovf)
{
    int pos = atomicAdd(&cursor[s * N_NODES + r], 1);   // group-private cursor
    if (pos < CAP) {
        // region[row][group][CAP]: 128B cell => 64B lines group-exclusive,
        // writes merge in the issuing XCD's L2.
        region[(r * 8 + s) * CAP + pos] = rc;
    } else {                                   // ~never (Poisson(8) tail), correct
        int o = atomicAdd(ovf_cnt, 1);
        if (o < OVF_CAP) ovf[o] = make_uint2((uint32)r, rc);
    }
}

// Fused: blocks [0,157) MFMA-GEMM h2 = pack_bf16(x @ W) with (c, c+64) column
// pairing; blocks [157,256) scatter edges into XCD-group capacity regions.
__global__ __launch_bounds__(256) void gemm_scatter_kernel(
    const float* __restrict__ x, const float* __restrict__ w,
    const int* __restrict__ row, const int* __restrict__ col,
    const float* __restrict__ val,
    uint32* __restrict__ h2, int* __restrict__ cursor,
    int* __restrict__ ovf_cnt, uint2* __restrict__ ovf,
    uint32* __restrict__ region)
{
    if (blockIdx.x >= GEMM_BLOCKS) {
        const int xcc = blockIdx.x & 7;     // round-robin block->XCD locality
        const int tid    = (blockIdx.x - GEMM_BLOCKS) * 256 + threadIdx.x;
        const int stride = SCAT_BLOCKS * 256;
        const int4*   row4 = (const int4*)row;
        const int4*   col4 = (const int4*)col;
        const float4* val4 = (const float4*)val;
        for (int i = tid; i < N_EDGES / 4; i += stride) {
            int4 r = row4[i]; int4 c = col4[i]; float4 v = val4[i];
            scat_one(r.x, (uint32)c.x | (f2bf_bits(v.x) << 16), xcc, cursor, region, ovf_cnt, ovf);
            scat_one(r.y, (uint32)c.y | (f2bf_bits(v.y) << 16), xcc, cursor, region, ovf_cnt, ovf);
            scat_one(r.z, (uint32)c.z | (f2bf_bits(v.z) << 16), xcc, cursor, region, ovf_cnt, ovf);
            scat_one(r.w, (uint32)c.w | (f2bf_bits(v.w) << 16), xcc, cursor, region, ovf_cnt, ovf);
        }
        return;
    }

    // ---- MFMA GEMM: 64 rows/block, 4 waves x 16 rows x 128 cols.
    // A layout: A[m=lane&15][k=quad*8+j]; B mirrors (k-major per lane) => W
    // staged col-major so each frag is one 16B LDS read. C/D: col=lane&15,
    // row=quad*4+reg (HW-verified m89/m91).
    __shared__ u16 Xs[64 * LSTR];    // 17408 B, bf16 row-major
    __shared__ u16 Ws[128 * LSTR];   // 34816 B, bf16 col-major: Ws[c*LSTR + k]
    const int t = threadIdx.x;

    #pragma unroll
    for (int i = 0; i < 8; ++i) {                 // stage x tile (64x128)
        int lin = t + i * 256;                    // float4 index
        int rw  = lin >> 5;
        int f4  = lin & 31;
        int gr = blockIdx.x * 64 + rw;
        if (gr >= N_NODES) gr = N_NODES - 1;
        float4 xv = *(const float4*)&x[(size_t)gr * D + f4 * 4];
        *(uint2*)&Xs[rw * LSTR + f4 * 4] =
            make_uint2(pack2(xv.x, xv.y), pack2(xv.z, xv.w));
    }
    #pragma unroll
    for (int i = 0; i < 32; ++i) {                // stage W transposed (128x128)
        int lin = t + i * 256;                    // k-pair x col index
        int c = lin & 127;
        int m = lin >> 7;
        float w0 = w[(2 * m) * D + c];
        float w1 = w[(2 * m + 1) * D + c];
        *(uint32*)&Ws[c * LSTR + 2 * m] = pack2(w0, w1);
    }
    __syncthreads();

    const int wv = t >> 6, lane = t & 63;
    const int q = lane >> 4, cl = lane & 15;
    f32x4 acc[8] = {};
    const u16* arow = &Xs[(wv * 16 + cl) * LSTR];
    #pragma unroll
    for (int k0 = 0; k0 < D; k0 += 32) {
        short8 af = *(const short8*)&arow[k0 + q * 8];
        #pragma unroll
        for (int ct = 0; ct < 8; ++ct) {
            short8 bf = *(const short8*)&Ws[(ct * 16 + cl) * LSTR + k0 + q * 8];
            acc[ct] = __builtin_amdgcn_mfma_f32_16x16x32_bf16(af, bf, acc[ct], 0, 0, 0);
        }
    }
    // h2[node*64 + c] packs cols (c, c+64): same lane holds tiles ct and ct+4
    // for the same (row, col%16) -> no cross-lane epilogue.
    #pragma unroll
    for (int reg = 0; reg < 4; ++reg) {
        int node = blockIdx.x * 64 + wv * 16 + q * 4 + reg;
        if (node < N_NODES) {
            uint32* base = h2 + (size_t)node * 64 + cl;
            #pragma unroll
            for (int ct = 0; ct < 4; ++ct)
                base[ct * 16] = pack2(acc[ct][reg], acc[ct + 4][reg]);
        }
    }
}

// Wave-per-row SpMM, zero LDS. Row's 8 segments are one contiguous 1KB block:
// 4 vector loads (lane<32 -> seg 2i, lane>=32 -> seg 2i+1). Gather loop
// unrolled x4: 4 readlane broadcasts -> 4 independent L2 gathers -> 8 FMA.
// h2 lane l holds cols (l, l+64).
__global__ __launch_bounds__(256) void spmm_kernel(
    const uint32* __restrict__ region, const int* __restrict__ cursor,
    const int* __restrict__ ovf_cnt, const uint2* __restrict__ ovf,
    const uint32* __restrict__ h2, const float* __restrict__ bias,
    float* __restrict__ out)
{
    const int t = threadIdx.x;
    const int lane = t & 63;
    const int r = blockIdx.x * 4 + (t >> 6);

    uint32 rl[4];
    #pragma unroll
    for (int i = 0; i < 4; ++i)
        rl[i] = region[r * 256 + i * 64 + lane];
    int ns[8];
    #pragma unroll
    for (int s = 0; s < 8; ++s) {
        int c = cursor[s * N_NODES + r];
        ns[s] = (c < CAP) ? c : CAP;
    }

    float a0 = 0.f, a1 = 0.f;
    #pragma unroll
    for (int s = 0; s < 8; ++s) {
        const int v    = (int)rl[s >> 1];
        const int half = (s & 1) * 32;
        const int n    = ns[s];
        int j = 0;
        for (; j + 4 <= n; j += 4) {
            uint32 q0 = (uint32)__builtin_amdgcn_readlane(v, half + j);
            uint32 q1 = (uint32)__builtin_amdgcn_readlane(v, half + j + 1);
            uint32 q2 = (uint32)__builtin_amdgcn_readlane(v, half + j + 2);
            uint32 q3 = (uint32)__builtin_amdgcn_readlane(v, half + j + 3);
            uint32 h0 = h2[((q0 & 0xFFFFu) << 6) + lane];
            uint32 h1 = h2[((q1 & 0xFFFFu) << 6) + lane];
            uint32 h2v = h2[((q2 & 0xFFFFu) << 6) + lane];
            uint32 h3 = h2[((q3 & 0xFFFFu) << 6) + lane];
            a0 = fmaf(__uint_as_float(q0 & 0xFFFF0000u), __uint_as_float(h0 << 16), a0);
            a1 = fmaf(__uint_as_float(q0 & 0xFFFF0000u), __uint_as_float(h0 & 0xFFFF0000u), a1);
            a0 = fmaf(__uint_as_float(q1 & 0xFFFF0000u), __uint_as_float(h1 << 16), a0);
            a1 = fmaf(__uint_as_float(q1 & 0xFFFF0000u), __uint_as_float(h1 & 0xFFFF0000u), a1);
            a0 = fmaf(__uint_as_float(q2 & 0xFFFF0000u), __uint_as_float(h2v << 16), a0);
            a1 = fmaf(__uint_as_float(q2 & 0xFFFF0000u), __uint_as_float(h2v & 0xFFFF0000u), a1);
            a0 = fmaf(__uint_as_float(q3 & 0xFFFF0000u), __uint_as_float(h3 << 16), a0);
            a1 = fmaf(__uint_as_float(q3 & 0xFFFF0000u), __uint_as_float(h3 & 0xFFFF0000u), a1);
        }
        for (; j < n; ++j) {
            uint32 q0 = (uint32)__builtin_amdgcn_readlane(v, half + j);
            uint32 h0 = h2[((q0 & 0xFFFFu) << 6) + lane];
            a0 = fmaf(__uint_as_float(q0 & 0xFFFF0000u), __uint_as_float(h0 << 16), a0);
            a1 = fmaf(__uint_as_float(q0 & 0xFFFF0000u), __uint_as_float(h0 & 0xFFFF0000u), a1);
        }
    }

    int novf = ovf_cnt[0];                 // expected 0
    if (novf > OVF_CAP) novf = OVF_CAP;
    for (int k = 0; k < novf; ++k) {
        uint2 e = ovf[k];
        if (e.x == (uint32)r) {
            uint32 qq = e.y;
            uint32 hv = h2[((qq & 0xFFFFu) << 6) + lane];
            a0 = fmaf(__uint_as_float(qq & 0xFFFF0000u), __uint_as_float(hv << 16), a0);
            a1 = fmaf(__uint_as_float(qq & 0xFFFF0000u), __uint_as_float(hv & 0xFFFF0000u), a1);
        }
    }

    out[(size_t)r * D + lane]      = a0 + bias[lane];
    out[(size_t)r * D + 64 + lane] = a1 + bias[lane + 64];
}

extern "C" void kernel_launch(void* const* d_in, const int* in_sizes, int n_in,
                              void* d_out, int out_size, void* d_ws, size_t ws_size,
                              hipStream_t stream)
{
    const float* x    = (const float*)d_in[0];
    const float* aval = (const float*)d_in[1];
    const float* w    = (const float*)d_in[2];
    const float* bias = (const float*)d_in[3];
    const int* arow   = (const int*)d_in[4];
    const int* acol   = (const int*)d_in[5];

    char* ws = (char*)d_ws;
    uint32* h2     = (uint32*)(ws);               //  2,560,000 B
    int*    cursor = (int*)(ws + 2560000);        //    320,000 B (8 x 10000)
    int*    ovfcnt = (int*)(ws + 2880000);        //          4 B (+pad)
    uint2*  ovf    = (uint2*)(ws + 2880064);      //     65,536 B
    uint32* region = (uint32*)(ws + 2945600);     // 10,240,000 B  (~13.2 MB)

    hipMemsetAsync(ws + 2560000, 0, 320004, stream);  // cursor + ovf_cnt

    gemm_scatter_kernel<<<GEMM_BLOCKS + SCAT_BLOCKS, 256, 0, stream>>>(
        x, w, arow, acol, aval, h2, cursor, ovfcnt, ovf, region);
    spmm_kernel<<<N_NODES / 4, 256, 0, stream>>>(
        region, cursor, ovfcnt, ovf, h2, bias, (float*)d_out);
}

// Round 7
// 119.956 us; speedup vs baseline: 2.4940x; 1.0632x over previous
//
#include <hip/hip_runtime.h>

#define N_NODES 10000
#define N_EDGES 640000
#define D 128

#define GEMM_BLOCKS 157   // 64 nodes per block (MFMA)
#define TOT_BLOCKS 256    // ALL blocks run the scatter loop (R7 change)
#define CAP 32            // per-(row,xcd-group) capacity (mean ~8)
#define OVF_CAP 8192
#define LSTR 136          // LDS row stride in ushorts: 272B, 16B-aligned, 2-way banks

typedef unsigned int uint32;
typedef unsigned short u16;
using short8 = __attribute__((ext_vector_type(8))) short;
using f32x4  = __attribute__((ext_vector_type(4))) float;

__device__ __forceinline__ uint32 f2bf_bits(float f) {
    uint32 u = __float_as_uint(f);
    return (u + 0x7FFFu + ((u >> 16) & 1u)) >> 16;   // RNE bf16 bits
}
__device__ __forceinline__ uint32 pack2(float lo, float hi) {
    return f2bf_bits(lo) | (f2bf_bits(hi) << 16);
}

__device__ __forceinline__ void scat_one(int r, uint32 rc, int s,
                                         int* __restrict__ cursor,
                                         uint32* __restrict__ region,
                                         int* ovf_cnt, uint2* ovf)
{
    int pos = atomicAdd(&cursor[s * N_NODES + r], 1);   // group-private cursor
    if (pos < CAP) {
        // region[row][group][CAP]: 128B cell => 64B lines group-exclusive,
        // writes merge in the issuing XCD's L2.
        region[(r * 8 + s) * CAP + pos] = rc;
    } else {                                   // ~never (Poisson(8) tail), correct
        int o = atomicAdd(ovf_cnt, 1);
        if (o < OVF_CAP) ovf[o] = make_uint2((uint32)r, rc);
    }
}

// Fused: blocks [0,157) first do their MFMA-GEMM tile (h2 = pack_bf16(x@W),
// (c,c+64) column pairing); then ALL 256 blocks grid-stride the edge list,
// scattering into XCD-group capacity regions (group = blockIdx&7).
__global__ __launch_bounds__(256) void gemm_scatter_kernel(
    const float* __restrict__ x, const float* __restrict__ w,
    const int* __restrict__ row, const int* __restrict__ col,
    const float* __restrict__ val,
    uint32* __restrict__ h2, int* __restrict__ cursor,
    int* __restrict__ ovf_cnt, uint2* __restrict__ ovf,
    uint32* __restrict__ region)
{
    const int t = threadIdx.x;

    if (blockIdx.x < GEMM_BLOCKS) {
        // ---- MFMA GEMM: 64 rows/block, 4 waves x 16 rows x 128 cols.
        // A[m=lane&15][k=quad*8+j]; B mirrors (k-major per lane) => W staged
        // col-major, each frag one 16B LDS read. C/D: col=lane&15,
        // row=quad*4+reg (HW-verified m89/m91; absmax confirms R6).
        __shared__ u16 Xs[64 * LSTR];    // 17408 B, bf16 row-major
        __shared__ u16 Ws[128 * LSTR];   // 34816 B, bf16 col-major Ws[c*LSTR+k]

        #pragma unroll
        for (int i = 0; i < 8; ++i) {                 // stage x tile (64x128)
            int lin = t + i * 256;                    // float4 index
            int rw  = lin >> 5;
            int f4  = lin & 31;
            int gr = blockIdx.x * 64 + rw;
            if (gr >= N_NODES) gr = N_NODES - 1;
            float4 xv = *(const float4*)&x[(size_t)gr * D + f4 * 4];
            *(uint2*)&Xs[rw * LSTR + f4 * 4] =
                make_uint2(pack2(xv.x, xv.y), pack2(xv.z, xv.w));
        }
        #pragma unroll
        for (int i = 0; i < 32; ++i) {                // stage W^T (128x128)
            int lin = t + i * 256;                    // k-pair x col index
            int c = lin & 127;
            int m = lin >> 7;
            float w0 = w[(2 * m) * D + c];
            float w1 = w[(2 * m + 1) * D + c];
            *(uint32*)&Ws[c * LSTR + 2 * m] = pack2(w0, w1);
        }
        __syncthreads();

        const int wv = t >> 6, lane = t & 63;
        const int q = lane >> 4, cl = lane & 15;
        f32x4 acc[8] = {};
        const u16* arow = &Xs[(wv * 16 + cl) * LSTR];
        #pragma unroll
        for (int k0 = 0; k0 < D; k0 += 32) {
            short8 af = *(const short8*)&arow[k0 + q * 8];
            #pragma unroll
            for (int ct = 0; ct < 8; ++ct) {
                short8 bf = *(const short8*)&Ws[(ct * 16 + cl) * LSTR + k0 + q * 8];
                acc[ct] = __builtin_amdgcn_mfma_f32_16x16x32_bf16(af, bf, acc[ct], 0, 0, 0);
            }
        }
        // h2[node*64 + c] packs cols (c, c+64): same lane holds tiles ct, ct+4.
        #pragma unroll
        for (int reg = 0; reg < 4; ++reg) {
            int node = blockIdx.x * 64 + wv * 16 + q * 4 + reg;
            if (node < N_NODES) {
                uint32* base = h2 + (size_t)node * 64 + cl;
                #pragma unroll
                for (int ct = 0; ct < 4; ++ct)
                    base[ct * 16] = pack2(acc[ct][reg], acc[ct + 4][reg]);
            }
        }
    }

    // ---- Scatter (all blocks): ~10 edges/thread grid-stride.
    {
        const int xcc = blockIdx.x & 7;     // round-robin block->XCD locality
        const int tid    = blockIdx.x * 256 + t;
        const int stride = TOT_BLOCKS * 256;
        const int4*   row4 = (const int4*)row;
        const int4*   col4 = (const int4*)col;
        const float4* val4 = (const float4*)val;
        for (int i = tid; i < N_EDGES / 4; i += stride) {
            int4 r = row4[i]; int4 c = col4[i]; float4 v = val4[i];
            scat_one(r.x, (uint32)c.x | (f2bf_bits(v.x) << 16), xcc, cursor, region, ovf_cnt, ovf);
            scat_one(r.y, (uint32)c.y | (f2bf_bits(v.y) << 16), xcc, cursor, region, ovf_cnt, ovf);
            scat_one(r.z, (uint32)c.z | (f2bf_bits(v.z) << 16), xcc, cursor, region, ovf_cnt, ovf);
            scat_one(r.w, (uint32)c.w | (f2bf_bits(v.w) << 16), xcc, cursor, region, ovf_cnt, ovf);
        }
    }
}

// Wave-per-row SpMM, zero LDS. Row's 8 segments = one contiguous 1KB block:
// 4 vector loads (lane<32 -> seg 2i, lane>=32 -> seg 2i+1). Gather loop
// unrolled x4: 4 readlane broadcasts -> 4 independent L2 gathers -> 8 FMA.
// h2 lane l holds cols (l, l+64).
__global__ __launch_bounds__(256) void spmm_kernel(
    const uint32* __restrict__ region, const int* __restrict__ cursor,
    const int* __restrict__ ovf_cnt, const uint2* __restrict__ ovf,
    const uint32* __restrict__ h2, const float* __restrict__ bias,
    float* __restrict__ out)
{
    const int t = threadIdx.x;
    const int lane = t & 63;
    const int r = blockIdx.x * 4 + (t >> 6);

    uint32 rl[4];
    #pragma unroll
    for (int i = 0; i < 4; ++i)
        rl[i] = region[r * 256 + i * 64 + lane];
    int ns[8];
    #pragma unroll
    for (int s = 0; s < 8; ++s) {
        int c = cursor[s * N_NODES + r];
        ns[s] = (c < CAP) ? c : CAP;
    }

    float a0 = 0.f, a1 = 0.f;
    #pragma unroll
    for (int s = 0; s < 8; ++s) {
        const int v    = (int)rl[s >> 1];
        const int half = (s & 1) * 32;
        const int n    = ns[s];
        int j = 0;
        for (; j + 4 <= n; j += 4) {
            uint32 q0 = (uint32)__builtin_amdgcn_readlane(v, half + j);
            uint32 q1 = (uint32)__builtin_amdgcn_readlane(v, half + j + 1);
            uint32 q2 = (uint32)__builtin_amdgcn_readlane(v, half + j + 2);
            uint32 q3 = (uint32)__builtin_amdgcn_readlane(v, half + j + 3);
            uint32 h0 = h2[((q0 & 0xFFFFu) << 6) + lane];
            uint32 h1 = h2[((q1 & 0xFFFFu) << 6) + lane];
            uint32 h2v = h2[((q2 & 0xFFFFu) << 6) + lane];
            uint32 h3 = h2[((q3 & 0xFFFFu) << 6) + lane];
            a0 = fmaf(__uint_as_float(q0 & 0xFFFF0000u), __uint_as_float(h0 << 16), a0);
            a1 = fmaf(__uint_as_float(q0 & 0xFFFF0000u), __uint_as_float(h0 & 0xFFFF0000u), a1);
            a0 = fmaf(__uint_as_float(q1 & 0xFFFF0000u), __uint_as_float(h1 << 16), a0);
            a1 = fmaf(__uint_as_float(q1 & 0xFFFF0000u), __uint_as_float(h1 & 0xFFFF0000u), a1);
            a0 = fmaf(__uint_as_float(q2 & 0xFFFF0000u), __uint_as_float(h2v << 16), a0);
            a1 = fmaf(__uint_as_float(q2 & 0xFFFF0000u), __uint_as_float(h2v & 0xFFFF0000u), a1);
            a0 = fmaf(__uint_as_float(q3 & 0xFFFF0000u), __uint_as_float(h3 << 16), a0);
            a1 = fmaf(__uint_as_float(q3 & 0xFFFF0000u), __uint_as_float(h3 & 0xFFFF0000u), a1);
        }
        for (; j < n; ++j) {
            uint32 q0 = (uint32)__builtin_amdgcn_readlane(v, half + j);
            uint32 h0 = h2[((q0 & 0xFFFFu) << 6) + lane];
            a0 = fmaf(__uint_as_float(q0 & 0xFFFF0000u), __uint_as_float(h0 << 16), a0);
            a1 = fmaf(__uint_as_float(q0 & 0xFFFF0000u), __uint_as_float(h0 & 0xFFFF0000u), a1);
        }
    }

    int novf = ovf_cnt[0];                 // expected 0
    if (novf > OVF_CAP) novf = OVF_CAP;
    for (int k = 0; k < novf; ++k) {
        uint2 e = ovf[k];
        if (e.x == (uint32)r) {
            uint32 qq = e.y;
            uint32 hv = h2[((qq & 0xFFFFu) << 6) + lane];
            a0 = fmaf(__uint_as_float(qq & 0xFFFF0000u), __uint_as_float(hv << 16), a0);
            a1 = fmaf(__uint_as_float(qq & 0xFFFF0000u), __uint_as_float(hv & 0xFFFF0000u), a1);
        }
    }

    out[(size_t)r * D + lane]      = a0 + bias[lane];
    out[(size_t)r * D + 64 + lane] = a1 + bias[lane + 64];
}

extern "C" void kernel_launch(void* const* d_in, const int* in_sizes, int n_in,
                              void* d_out, int out_size, void* d_ws, size_t ws_size,
                              hipStream_t stream)
{
    const float* x    = (const float*)d_in[0];
    const float* aval = (const float*)d_in[1];
    const float* w    = (const float*)d_in[2];
    const float* bias = (const float*)d_in[3];
    const int* arow   = (const int*)d_in[4];
    const int* acol   = (const int*)d_in[5];

    char* ws = (char*)d_ws;
    uint32* h2     = (uint32*)(ws);               //  2,560,000 B
    int*    cursor = (int*)(ws + 2560000);        //    320,000 B (8 x 10000)
    int*    ovfcnt = (int*)(ws + 2880000);        //          4 B (+pad)
    uint2*  ovf    = (uint2*)(ws + 2880064);      //     65,536 B
    uint32* region = (uint32*)(ws + 2945600);     // 10,240,000 B  (~13.2 MB)

    hipMemsetAsync(ws + 2560000, 0, 320004, stream);  // cursor + ovf_cnt

    gemm_scatter_kernel<<<TOT_BLOCKS, 256, 0, stream>>>(
        x, w, arow, acol, aval, h2, cursor, ovfcnt, ovf, region);
    spmm_kernel<<<N_NODES / 4, 256, 0, stream>>>(
        region, cursor, ovfcnt, ovf, h2, bias, (float*)d_out);
}

// Round 8
// 115.012 us; speedup vs baseline: 2.6012x; 1.0430x over previous
//
#include <hip/hip_runtime.h>

#define N_NODES 10000
#define N_EDGES 640000
#define D 128

#define GEMM_BLOCKS 157   // 64 nodes per block (MFMA)
#define TOT_BLOCKS 256    // all blocks run the scatter loop
#define CAP 32            // per-(row,xcd-group) capacity (mean ~8)
#define OVF_CAP 8192
#define LSTR 136          // LDS row stride in ushorts: 272B, 16B-aligned, 2-way banks
#define QPAD 272          // per-wave flat queue: 256 recs + 16 zero pad

typedef unsigned int uint32;
typedef unsigned short u16;
using short8 = __attribute__((ext_vector_type(8))) short;
using f32x4  = __attribute__((ext_vector_type(4))) float;

__device__ __forceinline__ uint32 f2bf_bits(float f) {
    uint32 u = __float_as_uint(f);
    return (u + 0x7FFFu + ((u >> 16) & 1u)) >> 16;   // RNE bf16 bits
}
__device__ __forceinline__ uint32 pack2(float lo, float hi) {
    return f2bf_bits(lo) | (f2bf_bits(hi) << 16);
}

__device__ __forceinline__ void scat_one(int r, uint32 rc, int s,
                                         int* __restrict__ cursor,
                                         uint32* __restrict__ region,
                                         int* ovf_cnt, uint2* ovf)
{
    int pos = atomicAdd(&cursor[s * N_NODES + r], 1);   // group-private cursor
    if (pos < CAP) {
        // region[row][group][CAP]: 128B cell => 64B lines group-exclusive,
        // writes merge in the issuing XCD's L2.
        region[(r * 8 + s) * CAP + pos] = rc;
    } else {                                   // ~never (Poisson(8) tail), correct
        int o = atomicAdd(ovf_cnt, 1);
        if (o < OVF_CAP) ovf[o] = make_uint2((uint32)r, rc);
    }
}

// Fused: blocks [0,157) first do their MFMA-GEMM tile (h2 = pack_bf16(x@W),
// (c,c+64) column pairing); then ALL 256 blocks grid-stride the edge list,
// scattering into XCD-group capacity regions (group = blockIdx&7).
__global__ __launch_bounds__(256) void gemm_scatter_kernel(
    const float* __restrict__ x, const float* __restrict__ w,
    const int* __restrict__ row, const int* __restrict__ col,
    const float* __restrict__ val,
    uint32* __restrict__ h2, int* __restrict__ cursor,
    int* __restrict__ ovf_cnt, uint2* __restrict__ ovf,
    uint32* __restrict__ region)
{
    const int t = threadIdx.x;

    if (blockIdx.x < GEMM_BLOCKS) {
        // ---- MFMA GEMM: 64 rows/block, 4 waves x 16 rows x 128 cols.
        // A[m=lane&15][k=quad*8+j]; B mirrors (k-major per lane) => W staged
        // col-major, each frag one 16B LDS read. C/D: col=lane&15,
        // row=quad*4+reg (HW-verified m89/m91; absmax confirms R6/R7).
        __shared__ u16 Xs[64 * LSTR];    // 17408 B, bf16 row-major
        __shared__ u16 Ws[128 * LSTR];   // 34816 B, bf16 col-major Ws[c*LSTR+k]

        #pragma unroll
        for (int i = 0; i < 8; ++i) {                 // stage x tile (64x128)
            int lin = t + i * 256;                    // float4 index
            int rw  = lin >> 5;
            int f4  = lin & 31;
            int gr = blockIdx.x * 64 + rw;
            if (gr >= N_NODES) gr = N_NODES - 1;
            float4 xv = *(const float4*)&x[(size_t)gr * D + f4 * 4];
            *(uint2*)&Xs[rw * LSTR + f4 * 4] =
                make_uint2(pack2(xv.x, xv.y), pack2(xv.z, xv.w));
        }
        #pragma unroll
        for (int i = 0; i < 32; ++i) {                // stage W^T (128x128)
            int lin = t + i * 256;                    // k-pair x col index
            int c = lin & 127;
            int m = lin >> 7;
            float w0 = w[(2 * m) * D + c];
            float w1 = w[(2 * m + 1) * D + c];
            *(uint32*)&Ws[c * LSTR + 2 * m] = pack2(w0, w1);
        }
        __syncthreads();

        const int wv = t >> 6, lane = t & 63;
        const int q = lane >> 4, cl = lane & 15;
        f32x4 acc[8] = {};
        const u16* arow = &Xs[(wv * 16 + cl) * LSTR];
        #pragma unroll
        for (int k0 = 0; k0 < D; k0 += 32) {
            short8 af = *(const short8*)&arow[k0 + q * 8];
            #pragma unroll
            for (int ct = 0; ct < 8; ++ct) {
                short8 bf = *(const short8*)&Ws[(ct * 16 + cl) * LSTR + k0 + q * 8];
                acc[ct] = __builtin_amdgcn_mfma_f32_16x16x32_bf16(af, bf, acc[ct], 0, 0, 0);
            }
        }
        // h2[node*64 + c] packs cols (c, c+64): same lane holds tiles ct, ct+4.
        #pragma unroll
        for (int reg = 0; reg < 4; ++reg) {
            int node = blockIdx.x * 64 + wv * 16 + q * 4 + reg;
            if (node < N_NODES) {
                uint32* base = h2 + (size_t)node * 64 + cl;
                #pragma unroll
                for (int ct = 0; ct < 4; ++ct)
                    base[ct * 16] = pack2(acc[ct][reg], acc[ct + 4][reg]);
            }
        }
    }

    // ---- Scatter (all blocks): ~10 edges/thread grid-stride.
    {
        const int xcc = blockIdx.x & 7;     // round-robin block->XCD locality
        const int tid    = blockIdx.x * 256 + t;
        const int stride = TOT_BLOCKS * 256;
        const int4*   row4 = (const int4*)row;
        const int4*   col4 = (const int4*)col;
        const float4* val4 = (const float4*)val;
        for (int i = tid; i < N_EDGES / 4; i += stride) {
            int4 r = row4[i]; int4 c = col4[i]; float4 v = val4[i];
            scat_one(r.x, (uint32)c.x | (f2bf_bits(v.x) << 16), xcc, cursor, region, ovf_cnt, ovf);
            scat_one(r.y, (uint32)c.y | (f2bf_bits(v.y) << 16), xcc, cursor, region, ovf_cnt, ovf);
            scat_one(r.z, (uint32)c.z | (f2bf_bits(v.z) << 16), xcc, cursor, region, ovf_cnt, ovf);
            scat_one(r.w, (uint32)c.w | (f2bf_bits(v.w) << 16), xcc, cursor, region, ovf_cnt, ovf);
        }
    }
}

// Wave-per-row SpMM. R8: per-wave LDS compaction of the row's 8 segments into
// a flat list, then a branch-free depth-8 software-pipelined gather loop
// (static register rotation, 8 L2 gathers always in flight). Zero-pad recs
// (val bits 0 => fma adds +0.0) kill all inner branches.
__global__ __launch_bounds__(256) void spmm_kernel(
    const uint32* __restrict__ region, const int* __restrict__ cursor,
    const int* __restrict__ ovf_cnt, const uint2* __restrict__ ovf,
    const uint32* __restrict__ h2, const float* __restrict__ bias,
    float* __restrict__ out)
{
    __shared__ uint32 qbuf[4 * QPAD];     // per-wave flat queues (4352 B)
    const int t = threadIdx.x;
    const int lane = t & 63;
    const int wid  = t >> 6;
    const int r = blockIdx.x * 4 + wid;
    uint32* qb = &qbuf[wid * QPAD];

    // preload the row's 1KB region block (segment s = cell>>5, pos = cell&31)
    uint32 rl[4];
    #pragma unroll
    for (int i = 0; i < 4; ++i)
        rl[i] = region[r * 256 + i * 64 + lane];

    // counts + prefix (wave-uniform scalars, computed redundantly per lane)
    int ns[8], pref[9];
    pref[0] = 0;
    #pragma unroll
    for (int s = 0; s < 8; ++s) {
        int c = cursor[s * N_NODES + r];
        ns[s] = (c < CAP) ? c : CAP;
        pref[s + 1] = pref[s] + ns[s];
    }
    const int ntot = pref[8];

    // compact valid recs to flat LDS list; for chunk i lanes<32 are segment
    // 2i (pos=lane&31), lanes>=32 segment 2i+1.
    #pragma unroll
    for (int i = 0; i < 4; ++i) {
        int p  = lane & 31;
        int hi = lane >> 5;                    // 0 or 1
        int n_  = hi ? ns[2 * i + 1]   : ns[2 * i];
        int pf  = hi ? pref[2 * i + 1] : pref[2 * i];
        if (p < n_) qb[pf + p] = rl[i];
    }
    if (lane < 16) qb[ntot + lane] = 0;        // zero pad (val=+0.0 recs)
    __builtin_amdgcn_s_waitcnt(0);             // drain LDS writes (wave-local)

    const int npad = (ntot + 7) & ~7;
    float a0 = 0.f, a1 = 0.f;

    uint32 rq0,rq1,rq2,rq3,rq4,rq5,rq6,rq7;
    uint32 hh0,hh1,hh2,hh3,hh4,hh5,hh6,hh7;
    // preload pipeline (slots always in-bounds thanks to pad)
    rq0 = qb[0]; hh0 = h2[((rq0 & 0xFFFFu) << 6) + lane];
    rq1 = qb[1]; hh1 = h2[((rq1 & 0xFFFFu) << 6) + lane];
    rq2 = qb[2]; hh2 = h2[((rq2 & 0xFFFFu) << 6) + lane];
    rq3 = qb[3]; hh3 = h2[((rq3 & 0xFFFFu) << 6) + lane];
    rq4 = qb[4]; hh4 = h2[((rq4 & 0xFFFFu) << 6) + lane];
    rq5 = qb[5]; hh5 = h2[((rq5 & 0xFFFFu) << 6) + lane];
    rq6 = qb[6]; hh6 = h2[((rq6 & 0xFFFFu) << 6) + lane];
    rq7 = qb[7]; hh7 = h2[((rq7 & 0xFFFFu) << 6) + lane];

#define CONSUME_PREFETCH(RQ, HH, P)                                          \
    {                                                                        \
        a0 = fmaf(__uint_as_float(RQ & 0xFFFF0000u),                         \
                  __uint_as_float(HH << 16), a0);                            \
        a1 = fmaf(__uint_as_float(RQ & 0xFFFF0000u),                         \
                  __uint_as_float(HH & 0xFFFF0000u), a1);                    \
        uint32 rn = qb[j + 8 + P];                                           \
        RQ = rn; HH = h2[((rn & 0xFFFFu) << 6) + lane];                      \
    }

    for (int j = 0; j < npad; j += 8) {
        CONSUME_PREFETCH(rq0, hh0, 0)
        CONSUME_PREFETCH(rq1, hh1, 1)
        CONSUME_PREFETCH(rq2, hh2, 2)
        CONSUME_PREFETCH(rq3, hh3, 3)
        CONSUME_PREFETCH(rq4, hh4, 4)
        CONSUME_PREFETCH(rq5, hh5, 5)
        CONSUME_PREFETCH(rq6, hh6, 6)
        CONSUME_PREFETCH(rq7, hh7, 7)
    }
#undef CONSUME_PREFETCH

    // overflow list (expected empty)
    int novf = ovf_cnt[0];
    if (novf > OVF_CAP) novf = OVF_CAP;
    for (int k = 0; k < novf; ++k) {
        uint2 e = ovf[k];
        if (e.x == (uint32)r) {
            uint32 qq = e.y;
            uint32 hv = h2[((qq & 0xFFFFu) << 6) + lane];
            a0 = fmaf(__uint_as_float(qq & 0xFFFF0000u), __uint_as_float(hv << 16), a0);
            a1 = fmaf(__uint_as_float(qq & 0xFFFF0000u), __uint_as_float(hv & 0xFFFF0000u), a1);
        }
    }

    out[(size_t)r * D + lane]      = a0 + bias[lane];
    out[(size_t)r * D + 64 + lane] = a1 + bias[lane + 64];
}

extern "C" void kernel_launch(void* const* d_in, const int* in_sizes, int n_in,
                              void* d_out, int out_size, void* d_ws, size_t ws_size,
                              hipStream_t stream)
{
    const float* x    = (const float*)d_in[0];
    const float* aval = (const float*)d_in[1];
    const float* w    = (const float*)d_in[2];
    const float* bias = (const float*)d_in[3];
    const int* arow   = (const int*)d_in[4];
    const int* acol   = (const int*)d_in[5];

    char* ws = (char*)d_ws;
    uint32* h2     = (uint32*)(ws);               //  2,560,000 B
    int*    cursor = (int*)(ws + 2560000);        //    320,000 B (8 x 10000)
    int*    ovfcnt = (int*)(ws + 2880000);        //          4 B (+pad)
    uint2*  ovf    = (uint2*)(ws + 2880064);      //     65,536 B
    uint32* region = (uint32*)(ws + 2945600);     // 10,240,000 B  (~13.2 MB)

    hipMemsetAsync(ws + 2560000, 0, 320004, stream);  // cursor + ovf_cnt

    gemm_scatter_kernel<<<TOT_BLOCKS, 256, 0, stream>>>(
        x, w, arow, acol, aval, h2, cursor, ovfcnt, ovf, region);
    spmm_kernel<<<N_NODES / 4, 256, 0, stream>>>(
        region, cursor, ovfcnt, ovf, h2, bias, (float*)d_out);
}